// Round 1
// baseline (456.965 us; speedup 1.0000x reference)
//
#include <hip/hip_runtime.h>
#include <cstddef>
#include <cstdint>

#define DIM   512
#define NSEQ  1024
#define NB    4
#define NHALF 4

// =====================================================================
// GEMM: out[m][n] = sum_k X[m][k] * W[n][k] + bias[n]
// M = NB*NSEQ = 4096, N = K = 512. Tile 64x64, BK=16, 256 thr, 4x4/thread.
// LDS row pad 68 (stride = 4 mod 32 -> <=2-way, free).
// =====================================================================
__global__ __launch_bounds__(256) void gemm512(const float* __restrict__ X,
                                               const float* __restrict__ W,
                                               const float* __restrict__ bias,
                                               float* __restrict__ out) {
  __shared__ float As[16][68];  // [k][m], transposed for vector m-reads
  __shared__ float Bs[16][68];  // [k][n]
  const int tid = threadIdx.x;
  const int tx = tid & 15, ty = tid >> 4;
  const int m0 = blockIdx.y * 64, n0 = blockIdx.x * 64;
  const int lr = tid >> 2, lc = tid & 3;  // loader: row 0..63, float4 col 0..3
  const float* xp = X + (size_t)(m0 + lr) * DIM + lc * 4;
  const float* wp = W + (size_t)(n0 + lr) * DIM + lc * 4;
  float acc[4][4] = {};
  for (int k0 = 0; k0 < DIM; k0 += 16) {
    const float4 av = *(const float4*)(xp + k0);
    const float4 bv = *(const float4*)(wp + k0);
    __syncthreads();  // previous iteration's reads done before overwrite
    As[lc * 4 + 0][lr] = av.x; As[lc * 4 + 1][lr] = av.y;
    As[lc * 4 + 2][lr] = av.z; As[lc * 4 + 3][lr] = av.w;
    Bs[lc * 4 + 0][lr] = bv.x; Bs[lc * 4 + 1][lr] = bv.y;
    Bs[lc * 4 + 2][lr] = bv.z; Bs[lc * 4 + 3][lr] = bv.w;
    __syncthreads();
#pragma unroll
    for (int kk = 0; kk < 16; ++kk) {
      const float4 a4 = *(const float4*)&As[kk][ty * 4];
      const float4 b4 = *(const float4*)&Bs[kk][tx * 4];
      const float aa[4] = {a4.x, a4.y, a4.z, a4.w};
      const float bb[4] = {b4.x, b4.y, b4.z, b4.w};
#pragma unroll
      for (int i = 0; i < 4; ++i)
#pragma unroll
        for (int j = 0; j < 4; ++j) acc[i][j] += aa[i] * bb[j];
    }
  }
  const float4 bb4 = *(const float4*)(bias + n0 + tx * 4);
  const float badd[4] = {bb4.x, bb4.y, bb4.z, bb4.w};
#pragma unroll
  for (int i = 0; i < 4; ++i) {
    float4 o;
    o.x = acc[i][0] + badd[0]; o.y = acc[i][1] + badd[1];
    o.z = acc[i][2] + badd[2]; o.w = acc[i][3] + badd[3];
    *(float4*)(out + (size_t)(m0 + ty * 4 + i) * DIM + n0 + tx * 4) = o;
  }
}

// =====================================================================
// Differential flash attention.
// Block = (qt, hp, b): 32 queries, head pair (hp, hp+4). 256 threads.
// Per K-tile (32 keys, both heads staged): register-blocked score GEMM
// (+RPE bias gather), dual online softmax (shfl over 16-lane k-groups),
// probs via LDS, three PV accumulators:
//   Y1 = P_h @ V_h, Y2 = P_h4 @ V_h, Y3 = P_h4 @ V_h4
// Epilogue: out_h = (1+a)*Y1/l_h - a*lam*Y2/l_h4 ; out_h4 = Y3/l_h4.
// Thread map: tx=k/d cols, ty=q rows; interleaved {t, t+16} row/col pairs
// so strided LDS reads land on distinct bank quads (pad 68 = 4 mod 32).
// =====================================================================
__global__ __launch_bounds__(256) void attn_kernel(
    const float* __restrict__ qg, const float* __restrict__ kg,
    const float* __restrict__ vg, const int* __restrict__ cq,
    const int* __restrict__ ck, const float* __restrict__ amap,
    const float* __restrict__ lq1, const float* __restrict__ lk1,
    const float* __restrict__ lq2, const float* __restrict__ lk2,
    const float* __restrict__ rpe, float* __restrict__ xo) {
  __shared__ float Qs[2][32][68];
  __shared__ float Ks[2][32][68];
  __shared__ float Vs[2][32][68];
  __shared__ float Ps[2][32][36];
  __shared__ int cqs[32][2];
  __shared__ int cks[32][2];
  __shared__ float alphas[32];
  __shared__ float lam_s;

  const int tid = threadIdx.x;
  const int tx = tid & 15, ty = tid >> 4;
  const int qt = blockIdx.x, hp = blockIdx.y, b = blockIdx.z;
  const int q0 = qt * 32;
  const int dx = tx * 4;

  // ---- stage Q for both heads, pre-scaled by HD^-0.5 = 1/8 ----
#pragma unroll
  for (int i = 0; i < 4; ++i) {
    const int f = i * 256 + tid;           // float4 id 0..1023
    const int h = f >> 9, g = f & 511;
    const int r = g >> 4, c4 = g & 15;
    const float4 v = *(const float4*)(qg + (size_t)(b * NSEQ + q0 + r) * DIM +
                                      hp * 64 + h * 256 + c4 * 4);
    float* d = &Qs[h][r][c4 * 4];
    d[0] = v.x * 0.125f; d[1] = v.y * 0.125f;
    d[2] = v.z * 0.125f; d[3] = v.w * 0.125f;
  }
  if (tid < 32) {
    cqs[tid][0] = cq[(b * NSEQ + q0 + tid) * 2 + 0];
    cqs[tid][1] = cq[(b * NSEQ + q0 + tid) * 2 + 1];
    alphas[tid] = amap[b * NSEQ + q0 + tid];
  }
  // ---- lambda for this head pair (wave 0 reduces 64 products) ----
  if (tid < 64) {
    float p1 = lq1[hp * 64 + tid] * lk1[hp * 64 + tid];
    float p2 = lq2[hp * 64 + tid] * lk2[hp * 64 + tid];
#pragma unroll
    for (int m = 32; m >= 1; m >>= 1) {
      p1 += __shfl_xor(p1, m, 64);
      p2 += __shfl_xor(p2, m, 64);
    }
    if (tid == 0) lam_s = __expf(p1) - __expf(p2) + 0.8f;
  }

  float m_run[2][2], l_run[2][2];
  float acc1[2][4] = {}, acc2[2][4] = {}, acc3[2][4] = {};
#pragma unroll
  for (int h = 0; h < 2; ++h)
#pragma unroll
    for (int j = 0; j < 2; ++j) { m_run[h][j] = -1e30f; l_run[h][j] = 0.0f; }

  for (int kt = 0; kt < NSEQ / 32; ++kt) {
    const int k0 = kt * 32;
    __syncthreads();  // prior PV reads of Ps/Vs (and init staging) complete
    // ---- stage K and V tiles (both heads) ----
#pragma unroll
    for (int i = 0; i < 8; ++i) {
      const int f = i * 256 + tid;        // float4 id 0..2047
      const int a = f >> 10, g = f & 1023;
      const int h = g >> 9, g2 = g & 511;
      const int r = g2 >> 4, c4 = g2 & 15;
      const float* src = a ? vg : kg;
      const float4 v = *(const float4*)(src + (size_t)(b * NSEQ + k0 + r) * DIM +
                                        hp * 64 + h * 256 + c4 * 4);
      float* d = a ? &Vs[h][r][c4 * 4] : &Ks[h][r][c4 * 4];
      d[0] = v.x; d[1] = v.y; d[2] = v.z; d[3] = v.w;
    }
    if (tid < 32) {
      cks[tid][0] = ck[(b * NSEQ + k0 + tid) * 2 + 0];
      cks[tid][1] = ck[(b * NSEQ + k0 + tid) * 2 + 1];
    }
    __syncthreads();

    // ---- RPE bias gather (issued early; idx shared across the 2 heads) ----
    float bias_[2][2][2];
#pragma unroll
    for (int jq = 0; jq < 2; ++jq) {
      const int qq = ty + jq * 16;
      const int a0 = cqs[qq][0], a1 = cqs[qq][1];
#pragma unroll
      for (int jk = 0; jk < 2; ++jk) {
        const int kk = tx + jk * 16;
        int r0 = a0 - cks[kk][0] + 128;
        int r1 = a1 - cks[kk][1] + 128;
        r0 = min(max(r0, 0), 256);
        r1 = min(max(r1, 0), 256);
        const int idx = (r0 * 257 + r1) * 8 + hp;
        bias_[0][jq][jk] = rpe[idx];
        bias_[1][jq][jk] = rpe[idx + 4];
      }
    }

    // ---- scores: s[h][jq][jk] = q_row . k_row ----
    float s[2][2][2] = {};
#pragma unroll
    for (int dc = 0; dc < 16; ++dc) {
      float qv[2][2][4], kv[2][2][4];
#pragma unroll
      for (int h = 0; h < 2; ++h)
#pragma unroll
        for (int j = 0; j < 2; ++j) {
          const float4 a = *(const float4*)&Qs[h][ty + j * 16][dc * 4];
          qv[h][j][0] = a.x; qv[h][j][1] = a.y; qv[h][j][2] = a.z; qv[h][j][3] = a.w;
          const float4 c = *(const float4*)&Ks[h][tx + j * 16][dc * 4];
          kv[h][j][0] = c.x; kv[h][j][1] = c.y; kv[h][j][2] = c.z; kv[h][j][3] = c.w;
        }
#pragma unroll
      for (int h = 0; h < 2; ++h)
#pragma unroll
        for (int jq = 0; jq < 2; ++jq)
#pragma unroll
          for (int jk = 0; jk < 2; ++jk)
#pragma unroll
            for (int e = 0; e < 4; ++e) s[h][jq][jk] += qv[h][jq][e] * kv[h][jk][e];
    }

    // ---- dual online softmax (rows live across the 16 tx lanes) ----
    float pr[2][2][2], af[2][2];
#pragma unroll
    for (int h = 0; h < 2; ++h)
#pragma unroll
      for (int jq = 0; jq < 2; ++jq) {
        const float s0 = s[h][jq][0] + bias_[h][jq][0];
        const float s1 = s[h][jq][1] + bias_[h][jq][1];
        float mx = fmaxf(s0, s1);
#pragma unroll
        for (int m = 8; m >= 1; m >>= 1) mx = fmaxf(mx, __shfl_xor(mx, m, 64));
        const float mnew = fmaxf(m_run[h][jq], mx);
        const float a = __expf(m_run[h][jq] - mnew);
        const float p0 = __expf(s0 - mnew);
        const float p1 = __expf(s1 - mnew);
        float ps = p0 + p1;
#pragma unroll
        for (int m = 8; m >= 1; m >>= 1) ps += __shfl_xor(ps, m, 64);
        l_run[h][jq] = l_run[h][jq] * a + ps;
        m_run[h][jq] = mnew;
        af[h][jq] = a;
        pr[h][jq][0] = p0; pr[h][jq][1] = p1;
      }
#pragma unroll
    for (int jq = 0; jq < 2; ++jq)
#pragma unroll
      for (int jd = 0; jd < 4; ++jd) {
        acc1[jq][jd] *= af[0][jq];
        acc2[jq][jd] *= af[1][jq];
        acc3[jq][jd] *= af[1][jq];
      }
#pragma unroll
    for (int h = 0; h < 2; ++h)
#pragma unroll
      for (int jq = 0; jq < 2; ++jq)
#pragma unroll
        for (int jk = 0; jk < 2; ++jk)
          Ps[h][ty + jq * 16][tx + jk * 16] = pr[h][jq][jk];
    __syncthreads();

    // ---- PV: three accumulators ----
#pragma unroll
    for (int kc = 0; kc < 8; ++kc) {
      float pa[2][2][4];
#pragma unroll
      for (int h = 0; h < 2; ++h)
#pragma unroll
        for (int jq = 0; jq < 2; ++jq) {
          const float4 p = *(const float4*)&Ps[h][ty + jq * 16][kc * 4];
          pa[h][jq][0] = p.x; pa[h][jq][1] = p.y; pa[h][jq][2] = p.z; pa[h][jq][3] = p.w;
        }
#pragma unroll
      for (int j = 0; j < 4; ++j) {
        const float4 v0 = *(const float4*)&Vs[0][kc * 4 + j][dx];
        const float4 v1 = *(const float4*)&Vs[1][kc * 4 + j][dx];
        const float v0a[4] = {v0.x, v0.y, v0.z, v0.w};
        const float v1a[4] = {v1.x, v1.y, v1.z, v1.w};
#pragma unroll
        for (int jq = 0; jq < 2; ++jq) {
          const float w1 = pa[0][jq][j];
          const float w2 = pa[1][jq][j];
#pragma unroll
          for (int jd = 0; jd < 4; ++jd) {
            acc1[jq][jd] += w1 * v0a[jd];
            acc2[jq][jd] += w2 * v0a[jd];
            acc3[jq][jd] += w2 * v1a[jd];
          }
        }
      }
    }
  }

  // ---- epilogue: normalize + differential combine, write (B,Nq,512) ----
  const float lam = lam_s;
#pragma unroll
  for (int jq = 0; jq < 2; ++jq) {
    const int qq = ty + jq * 16;
    const float al = alphas[qq];
    const float i1 = 1.0f / l_run[0][jq];
    const float i2 = 1.0f / l_run[1][jq];
    float o1[4], o2[4];
#pragma unroll
    for (int jd = 0; jd < 4; ++jd) {
      const float y1 = acc1[jq][jd] * i1;
      const float y2 = acc2[jq][jd] * i2;
      o1[jd] = (1.0f + al) * y1 - al * lam * y2;
      o2[jd] = acc3[jq][jd] * i2;
    }
    float* base = xo + (size_t)(b * NSEQ + q0 + qq) * DIM;
    *(float4*)(base + hp * 64 + dx) = make_float4(o1[0], o1[1], o1[2], o1[3]);
    *(float4*)(base + (hp + 4) * 64 + dx) = make_float4(o2[0], o2[1], o2[2], o2[3]);
  }
}

// =====================================================================
extern "C" void kernel_launch(void* const* d_in, const int* in_sizes, int n_in,
                              void* d_out, int out_size, void* d_ws, size_t ws_size,
                              hipStream_t stream) {
  const float* x_q   = (const float*)d_in[0];
  const float* x_kv  = (const float*)d_in[1];
  const int*   c_q   = (const int*)d_in[2];
  const int*   c_k   = (const int*)d_in[3];
  const float* alpha = (const float*)d_in[4];
  const float* Wq    = (const float*)d_in[5];
  const float* bq    = (const float*)d_in[6];
  const float* Wk    = (const float*)d_in[7];
  const float* bk    = (const float*)d_in[8];
  const float* Wv    = (const float*)d_in[9];
  const float* bv    = (const float*)d_in[10];
  const float* lq1   = (const float*)d_in[11];
  const float* lk1   = (const float*)d_in[12];
  const float* lq2   = (const float*)d_in[13];
  const float* lk2   = (const float*)d_in[14];
  const float* rpe   = (const float*)d_in[15];
  const float* Wp    = (const float*)d_in[16];
  const float* bp    = (const float*)d_in[17];
  float* out = (float*)d_out;

  const size_t plane = (size_t)NB * NSEQ * DIM;  // 2M floats = 8 MB
  float* qw = (float*)d_ws;
  float* kw = qw + plane;
  float* vw = kw + plane;
  float* xa = vw + plane;

  const dim3 gblk(DIM / 64, NB * NSEQ / 64);  // (8, 64)
  gemm512<<<gblk, 256, 0, stream>>>(x_q,  Wq, bq, qw);
  gemm512<<<gblk, 256, 0, stream>>>(x_kv, Wk, bk, kw);
  gemm512<<<gblk, 256, 0, stream>>>(x_kv, Wv, bv, vw);
  attn_kernel<<<dim3(NSEQ / 32, NHALF, NB), 256, 0, stream>>>(
      qw, kw, vw, c_q, c_k, alpha, lq1, lk1, lq2, lk2, rpe, xa);
  gemm512<<<gblk, 256, 0, stream>>>(xa, Wp, bp, out);
}

// Round 2
// 392.545 us; speedup vs baseline: 1.1641x; 1.1641x over previous
//
#include <hip/hip_runtime.h>
#include <cstddef>
#include <cstdint>

#define DIM   512
#define NSEQ  1024
#define NB    4
#define NHALF 4

typedef unsigned short u16;
typedef short bf16x8 __attribute__((ext_vector_type(8)));
typedef float f32x4  __attribute__((ext_vector_type(4)));

// RNE fp32 -> bf16 split: x ~= hi + lo, each bf16 (error ~2^-18 * |x|)
__device__ inline void split2(float x, u16& h, u16& l) {
  unsigned u = __float_as_uint(x);
  unsigned hb = (u + 0x7fffu + ((u >> 16) & 1u)) >> 16;
  float fh = __uint_as_float(hb << 16);
  float r = x - fh;
  unsigned v = __float_as_uint(r);
  unsigned lb = (v + 0x7fffu + ((v >> 16) & 1u)) >> 16;
  h = (u16)hb; l = (u16)lb;
}

__device__ inline uint2 pack4(const u16 a[4]) {
  return make_uint2((unsigned)a[0] | ((unsigned)a[1] << 16),
                    (unsigned)a[2] | ((unsigned)a[3] << 16));
}

// fp32 [rows][512] -> u16 [rows][1024] (cols 0..511 = hi plane, 512..1023 = lo)
__device__ inline void split_body(const float* __restrict__ in,
                                  u16* __restrict__ out, int e4) {
  const int e = e4 * 4;
  const int m = e >> 9, c = e & 511;
  const float4 v = *(const float4*)(in + e);
  u16 h[4], l[4];
  split2(v.x, h[0], l[0]); split2(v.y, h[1], l[1]);
  split2(v.z, h[2], l[2]); split2(v.w, h[3], l[3]);
  u16* o = out + (size_t)m * 1024 + c;
  *(uint2*)o = pack4(h);
  *(uint2*)(o + 512) = pack4(l);
}

__global__ __launch_bounds__(256) void split_rows(const float* __restrict__ in,
                                                  u16* __restrict__ out) {
  split_body(in, out, blockIdx.x * 256 + threadIdx.x);
}

__global__ __launch_bounds__(256) void split_w4(
    const float* __restrict__ w0, const float* __restrict__ w1,
    const float* __restrict__ w2, const float* __restrict__ w3,
    u16* __restrict__ out) {
  const int y = blockIdx.y;
  const float* src = (y == 0) ? w0 : (y == 1) ? w1 : (y == 2) ? w2 : w3;
  split_body(src, out + (size_t)y * 524288, blockIdx.x * 256 + threadIdx.x);
}

#define GLDS(g, l)                                                        \
  __builtin_amdgcn_global_load_lds(                                       \
      (const __attribute__((address_space(1))) void*)(g),                 \
      (__attribute__((address_space(3))) void*)(l), 16, 0, 0)

// =====================================================================
// Split-bf16 MFMA GEMM: out[m][n] = sum_k X[m][k]*W[n][k] + bias[n]
// A2/B2: u16 [rows][1024] hi|lo planes. M=4096, N=512, K=512.
// 64x64 tile, 256 thr = 4 waves, wave -> 32x32 (2x2 of 16x16x32 MFMA),
// 3 split products (hh, hl, lh). LDS staged via global_load_lds w=16,
// XOR chunk swizzle (pos = chunk ^ (row&7)) -> uniform bank load.
// =====================================================================
__global__ __launch_bounds__(256) void gemm_split(
    const u16* __restrict__ A2, const u16* __restrict__ B2,
    const float* __restrict__ bias, float* __restrict__ out) {
  __shared__ __align__(16) u16 Ah[4096], Al[4096], Bh[4096], Bl[4096];
  const int tid  = threadIdx.x;
  const int lane = tid & 63, w = tid >> 6;
  const int m0 = blockIdx.y * 64, n0 = blockIdx.x * 64;
  const int wm = (w & 1) * 32, wn = (w >> 1) * 32;

  // ---- staging addresses (c in {0,1} adds 8 rows / 1024 LDS bytes) ----
  const int sr  = w * 16 + (lane >> 3);       // rows sr, sr+8
  const int sp  = lane & 7;
  const int scg = sp ^ (sr & 7);              // (sr+8)&7 == sr&7
  const size_t aR = (size_t)(m0 + sr) * 1024 + scg * 8;
  const size_t bR = (size_t)(n0 + sr) * 1024 + scg * 8;
  const u16* gAh0 = A2 + aR;            const u16* gAh1 = A2 + aR + 8192;
  const u16* gAl0 = A2 + aR + 512;      const u16* gAl1 = A2 + aR + 8704;
  const u16* gBh0 = B2 + bR;            const u16* gBh1 = B2 + bR + 8192;
  const u16* gBl0 = B2 + bR + 512;      const u16* gBl1 = B2 + bR + 8704;
  char* lAh = (char*)Ah + w * 2048;  char* lAl = (char*)Al + w * 2048;
  char* lBh = (char*)Bh + w * 2048;  char* lBl = (char*)Bl + w * 2048;

  // ---- fragment read offsets ----
  const int fr = lane & 15, kq = lane >> 4, fx = lane & 7;  // fx = fr&7
  int aoff[2][2], boff[2][2];  // [s][tile]
#pragma unroll
  for (int s = 0; s < 2; ++s)
#pragma unroll
    for (int t = 0; t < 2; ++t) {
      aoff[s][t] = (wm + t * 16 + fr) * 64 + (((s * 4 + kq) ^ fx)) * 8;
      boff[s][t] = (wn + t * 16 + fr) * 64 + (((s * 4 + kq) ^ fx)) * 8;
    }

  f32x4 acc[2][2] = {};
  for (int k0 = 0; k0 < 512; k0 += 64) {
    __syncthreads();  // prior reads of LDS complete
    GLDS(gAh0 + k0, lAh);  GLDS(gAh1 + k0, lAh + 1024);
    GLDS(gAl0 + k0, lAl);  GLDS(gAl1 + k0, lAl + 1024);
    GLDS(gBh0 + k0, lBh);  GLDS(gBh1 + k0, lBh + 1024);
    GLDS(gBl0 + k0, lBl);  GLDS(gBl1 + k0, lBl + 1024);
    __syncthreads();  // barrier drains vmcnt -> LDS valid
#pragma unroll
    for (int s = 0; s < 2; ++s) {
      bf16x8 ah[2], al[2], bh[2], bl[2];
#pragma unroll
      for (int t = 0; t < 2; ++t) {
        ah[t] = *(const bf16x8*)(Ah + aoff[s][t]);
        al[t] = *(const bf16x8*)(Al + aoff[s][t]);
        bh[t] = *(const bf16x8*)(Bh + boff[s][t]);
        bl[t] = *(const bf16x8*)(Bl + boff[s][t]);
      }
#pragma unroll
      for (int i = 0; i < 2; ++i)
#pragma unroll
        for (int j = 0; j < 2; ++j) {
          acc[i][j] = __builtin_amdgcn_mfma_f32_16x16x32_bf16(al[i], bh[j], acc[i][j], 0, 0, 0);
          acc[i][j] = __builtin_amdgcn_mfma_f32_16x16x32_bf16(ah[i], bl[j], acc[i][j], 0, 0, 0);
          acc[i][j] = __builtin_amdgcn_mfma_f32_16x16x32_bf16(ah[i], bh[j], acc[i][j], 0, 0, 0);
        }
    }
  }

  // ---- epilogue: C/D layout col=lane&15, row=(lane>>4)*4+r (m89-verified) ----
  const int er = (lane >> 4) * 4, ec = lane & 15;
#pragma unroll
  for (int i = 0; i < 2; ++i)
#pragma unroll
    for (int j = 0; j < 2; ++j) {
      const int row = m0 + wm + i * 16 + er;
      const int col = n0 + wn + j * 16 + ec;
      const float bv = bias[col];
#pragma unroll
      for (int r = 0; r < 4; ++r)
        out[(size_t)(row + r) * 512 + col] = acc[i][j][r] + bv;
    }
}

// =====================================================================
// Differential flash attention (unchanged from round 1 except epilogue:
// writes xa as split-bf16 [m][1024] hi|lo for the MFMA output GEMM).
// =====================================================================
__global__ __launch_bounds__(256) void attn_kernel(
    const float* __restrict__ qg, const float* __restrict__ kg,
    const float* __restrict__ vg, const int* __restrict__ cq,
    const int* __restrict__ ck, const float* __restrict__ amap,
    const float* __restrict__ lq1, const float* __restrict__ lk1,
    const float* __restrict__ lq2, const float* __restrict__ lk2,
    const float* __restrict__ rpe, u16* __restrict__ xo) {
  __shared__ float Qs[2][32][68];
  __shared__ float Ks[2][32][68];
  __shared__ float Vs[2][32][68];
  __shared__ float Ps[2][32][36];
  __shared__ int cqs[32][2];
  __shared__ int cks[32][2];
  __shared__ float alphas[32];
  __shared__ float lam_s;

  const int tid = threadIdx.x;
  const int tx = tid & 15, ty = tid >> 4;
  const int qt = blockIdx.x, hp = blockIdx.y, b = blockIdx.z;
  const int q0 = qt * 32;
  const int dx = tx * 4;

#pragma unroll
  for (int i = 0; i < 4; ++i) {
    const int f = i * 256 + tid;
    const int h = f >> 9, g = f & 511;
    const int r = g >> 4, c4 = g & 15;
    const float4 v = *(const float4*)(qg + (size_t)(b * NSEQ + q0 + r) * DIM +
                                      hp * 64 + h * 256 + c4 * 4);
    float* d = &Qs[h][r][c4 * 4];
    d[0] = v.x * 0.125f; d[1] = v.y * 0.125f;
    d[2] = v.z * 0.125f; d[3] = v.w * 0.125f;
  }
  if (tid < 32) {
    cqs[tid][0] = cq[(b * NSEQ + q0 + tid) * 2 + 0];
    cqs[tid][1] = cq[(b * NSEQ + q0 + tid) * 2 + 1];
    alphas[tid] = amap[b * NSEQ + q0 + tid];
  }
  if (tid < 64) {
    float p1 = lq1[hp * 64 + tid] * lk1[hp * 64 + tid];
    float p2 = lq2[hp * 64 + tid] * lk2[hp * 64 + tid];
#pragma unroll
    for (int m = 32; m >= 1; m >>= 1) {
      p1 += __shfl_xor(p1, m, 64);
      p2 += __shfl_xor(p2, m, 64);
    }
    if (tid == 0) lam_s = __expf(p1) - __expf(p2) + 0.8f;
  }

  float m_run[2][2], l_run[2][2];
  float acc1[2][4] = {}, acc2[2][4] = {}, acc3[2][4] = {};
#pragma unroll
  for (int h = 0; h < 2; ++h)
#pragma unroll
    for (int j = 0; j < 2; ++j) { m_run[h][j] = -1e30f; l_run[h][j] = 0.0f; }

  for (int kt = 0; kt < NSEQ / 32; ++kt) {
    const int k0 = kt * 32;
    __syncthreads();
#pragma unroll
    for (int i = 0; i < 8; ++i) {
      const int f = i * 256 + tid;
      const int a = f >> 10, g = f & 1023;
      const int h = g >> 9, g2 = g & 511;
      const int r = g2 >> 4, c4 = g2 & 15;
      const float* src = a ? vg : kg;
      const float4 v = *(const float4*)(src + (size_t)(b * NSEQ + k0 + r) * DIM +
                                        hp * 64 + h * 256 + c4 * 4);
      float* d = a ? &Vs[h][r][c4 * 4] : &Ks[h][r][c4 * 4];
      d[0] = v.x; d[1] = v.y; d[2] = v.z; d[3] = v.w;
    }
    if (tid < 32) {
      cks[tid][0] = ck[(b * NSEQ + k0 + tid) * 2 + 0];
      cks[tid][1] = ck[(b * NSEQ + k0 + tid) * 2 + 1];
    }
    __syncthreads();

    float bias_[2][2][2];
#pragma unroll
    for (int jq = 0; jq < 2; ++jq) {
      const int qq = ty + jq * 16;
      const int a0 = cqs[qq][0], a1 = cqs[qq][1];
#pragma unroll
      for (int jk = 0; jk < 2; ++jk) {
        const int kk = tx + jk * 16;
        int r0 = a0 - cks[kk][0] + 128;
        int r1 = a1 - cks[kk][1] + 128;
        r0 = min(max(r0, 0), 256);
        r1 = min(max(r1, 0), 256);
        const int idx = (r0 * 257 + r1) * 8 + hp;
        bias_[0][jq][jk] = rpe[idx];
        bias_[1][jq][jk] = rpe[idx + 4];
      }
    }

    float s[2][2][2] = {};
#pragma unroll
    for (int dc = 0; dc < 16; ++dc) {
      float qv[2][2][4], kv[2][2][4];
#pragma unroll
      for (int h = 0; h < 2; ++h)
#pragma unroll
        for (int j = 0; j < 2; ++j) {
          const float4 a = *(const float4*)&Qs[h][ty + j * 16][dc * 4];
          qv[h][j][0] = a.x; qv[h][j][1] = a.y; qv[h][j][2] = a.z; qv[h][j][3] = a.w;
          const float4 c = *(const float4*)&Ks[h][tx + j * 16][dc * 4];
          kv[h][j][0] = c.x; kv[h][j][1] = c.y; kv[h][j][2] = c.z; kv[h][j][3] = c.w;
        }
#pragma unroll
      for (int h = 0; h < 2; ++h)
#pragma unroll
        for (int jq = 0; jq < 2; ++jq)
#pragma unroll
          for (int jk = 0; jk < 2; ++jk)
#pragma unroll
            for (int e = 0; e < 4; ++e) s[h][jq][jk] += qv[h][jq][e] * kv[h][jk][e];
    }

    float pr[2][2][2], af[2][2];
#pragma unroll
    for (int h = 0; h < 2; ++h)
#pragma unroll
      for (int jq = 0; jq < 2; ++jq) {
        const float s0 = s[h][jq][0] + bias_[h][jq][0];
        const float s1 = s[h][jq][1] + bias_[h][jq][1];
        float mx = fmaxf(s0, s1);
#pragma unroll
        for (int m = 8; m >= 1; m >>= 1) mx = fmaxf(mx, __shfl_xor(mx, m, 64));
        const float mnew = fmaxf(m_run[h][jq], mx);
        const float a = __expf(m_run[h][jq] - mnew);
        const float p0 = __expf(s0 - mnew);
        const float p1 = __expf(s1 - mnew);
        float ps = p0 + p1;
#pragma unroll
        for (int m = 8; m >= 1; m >>= 1) ps += __shfl_xor(ps, m, 64);
        l_run[h][jq] = l_run[h][jq] * a + ps;
        m_run[h][jq] = mnew;
        af[h][jq] = a;
        pr[h][jq][0] = p0; pr[h][jq][1] = p1;
      }
#pragma unroll
    for (int jq = 0; jq < 2; ++jq)
#pragma unroll
      for (int jd = 0; jd < 4; ++jd) {
        acc1[jq][jd] *= af[0][jq];
        acc2[jq][jd] *= af[1][jq];
        acc3[jq][jd] *= af[1][jq];
      }
#pragma unroll
    for (int h = 0; h < 2; ++h)
#pragma unroll
      for (int jq = 0; jq < 2; ++jq)
#pragma unroll
        for (int jk = 0; jk < 2; ++jk)
          Ps[h][ty + jq * 16][tx + jk * 16] = pr[h][jq][jk];
    __syncthreads();

#pragma unroll
    for (int kc = 0; kc < 8; ++kc) {
      float pa[2][2][4];
#pragma unroll
      for (int h = 0; h < 2; ++h)
#pragma unroll
        for (int jq = 0; jq < 2; ++jq) {
          const float4 p = *(const float4*)&Ps[h][ty + jq * 16][kc * 4];
          pa[h][jq][0] = p.x; pa[h][jq][1] = p.y; pa[h][jq][2] = p.z; pa[h][jq][3] = p.w;
        }
#pragma unroll
      for (int j = 0; j < 4; ++j) {
        const float4 v0 = *(const float4*)&Vs[0][kc * 4 + j][dx];
        const float4 v1 = *(const float4*)&Vs[1][kc * 4 + j][dx];
        const float v0a[4] = {v0.x, v0.y, v0.z, v0.w};
        const float v1a[4] = {v1.x, v1.y, v1.z, v1.w};
#pragma unroll
        for (int jq = 0; jq < 2; ++jq) {
          const float w1 = pa[0][jq][j];
          const float w2 = pa[1][jq][j];
#pragma unroll
          for (int jd = 0; jd < 4; ++jd) {
            acc1[jq][jd] += w1 * v0a[jd];
            acc2[jq][jd] += w2 * v0a[jd];
            acc3[jq][jd] += w2 * v1a[jd];
          }
        }
      }
    }
  }

  // ---- epilogue: combine and emit split-bf16 xa [m][1024] ----
  const float lam = lam_s;
#pragma unroll
  for (int jq = 0; jq < 2; ++jq) {
    const int qq = ty + jq * 16;
    const float al = alphas[qq];
    const float i1 = 1.0f / l_run[0][jq];
    const float i2 = 1.0f / l_run[1][jq];
    float o1[4], o2[4];
#pragma unroll
    for (int jd = 0; jd < 4; ++jd) {
      const float y1 = acc1[jq][jd] * i1;
      const float y2 = acc2[jq][jd] * i2;
      o1[jd] = (1.0f + al) * y1 - al * lam * y2;
      o2[jd] = acc3[jq][jd] * i2;
    }
    const size_t base = (size_t)(b * NSEQ + q0 + qq) * 1024;
    u16 hh[4], ll[4];
#pragma unroll
    for (int jd = 0; jd < 4; ++jd) split2(o1[jd], hh[jd], ll[jd]);
    *(uint2*)(xo + base + hp * 64 + dx)       = pack4(hh);
    *(uint2*)(xo + base + 512 + hp * 64 + dx) = pack4(ll);
#pragma unroll
    for (int jd = 0; jd < 4; ++jd) split2(o2[jd], hh[jd], ll[jd]);
    *(uint2*)(xo + base + (hp + 4) * 64 + dx)       = pack4(hh);
    *(uint2*)(xo + base + 512 + (hp + 4) * 64 + dx) = pack4(ll);
  }
}

// =====================================================================
extern "C" void kernel_launch(void* const* d_in, const int* in_sizes, int n_in,
                              void* d_out, int out_size, void* d_ws, size_t ws_size,
                              hipStream_t stream) {
  const float* x_q   = (const float*)d_in[0];
  const float* x_kv  = (const float*)d_in[1];
  const int*   c_q   = (const int*)d_in[2];
  const int*   c_k   = (const int*)d_in[3];
  const float* alpha = (const float*)d_in[4];
  const float* Wq    = (const float*)d_in[5];
  const float* bq    = (const float*)d_in[6];
  const float* Wk    = (const float*)d_in[7];
  const float* bk    = (const float*)d_in[8];
  const float* Wv    = (const float*)d_in[9];
  const float* bv    = (const float*)d_in[10];
  const float* lq1   = (const float*)d_in[11];
  const float* lk1   = (const float*)d_in[12];
  const float* lq2   = (const float*)d_in[13];
  const float* lk2   = (const float*)d_in[14];
  const float* rpe   = (const float*)d_in[15];
  const float* Wp    = (const float*)d_in[16];
  const float* bp    = (const float*)d_in[17];
  float* out = (float*)d_out;

  // ws layout (28 MB): kw[8M] vw[8M] x2[8M: xq2 -> xkv2 -> xa2] w2[4M]
  float* kw = (float*)d_ws;
  float* vw = (float*)((char*)d_ws + (8u << 20));
  u16*   x2 = (u16*)  ((char*)d_ws + (16u << 20));
  u16*   w2 = (u16*)  ((char*)d_ws + (24u << 20));
  float* qw = out;  // d_out doubles as q scratch until the final GEMM

  const dim3 gg(8, 64);  // N/64, M/64
  split_w4<<<dim3(256, 4), 256, 0, stream>>>(Wq, Wk, Wv, Wp, w2);
  split_rows<<<2048, 256, 0, stream>>>(x_q, x2);
  gemm_split<<<gg, 256, 0, stream>>>(x2, w2, bq, qw);
  split_rows<<<2048, 256, 0, stream>>>(x_kv, x2);
  gemm_split<<<gg, 256, 0, stream>>>(x2, w2 + 524288, bk, kw);
  gemm_split<<<gg, 256, 0, stream>>>(x2, w2 + 2 * 524288, bv, vw);
  attn_kernel<<<dim3(NSEQ / 32, NHALF, NB), 256, 0, stream>>>(
      qw, kw, vw, c_q, c_k, alpha, lq1, lk1, lq2, lk2, rpe, x2);
  gemm_split<<<gg, 256, 0, stream>>>(x2, w2 + 3 * 524288, bp, out);
}

// Round 3
// 309.034 us; speedup vs baseline: 1.4787x; 1.2702x over previous
//
#include <hip/hip_runtime.h>
#include <cstddef>
#include <cstdint>

#define DIM   512
#define NSEQ  1024
#define NB    4

typedef unsigned short u16;
typedef short bf16x8 __attribute__((ext_vector_type(8)));
typedef float f32x4  __attribute__((ext_vector_type(4)));

#define MFMA(a, b, c) __builtin_amdgcn_mfma_f32_16x16x32_bf16(a, b, c, 0, 0, 0)

// RNE fp32 -> bf16 split: x ~= hi + lo (error ~2^-18 * |x|)
__device__ inline void split2(float x, u16& h, u16& l) {
  unsigned u = __float_as_uint(x);
  unsigned hb = (u + 0x7fffu + ((u >> 16) & 1u)) >> 16;
  float fh = __uint_as_float(hb << 16);
  float r = x - fh;
  unsigned v = __float_as_uint(r);
  unsigned lb = (v + 0x7fffu + ((v >> 16) & 1u)) >> 16;
  h = (u16)hb; l = (u16)lb;
}

__device__ inline uint2 pack4(const u16 a[4]) {
  return make_uint2((unsigned)a[0] | ((unsigned)a[1] << 16),
                    (unsigned)a[2] | ((unsigned)a[3] << 16));
}

// fp32 [rows][512] -> u16 [rows][1024] (hi plane | lo plane)
__device__ inline void split_body(const float* __restrict__ in,
                                  u16* __restrict__ out, int e4) {
  const int e = e4 * 4;
  const int m = e >> 9, c = e & 511;
  const float4 v = *(const float4*)(in + e);
  u16 h[4], l[4];
  split2(v.x, h[0], l[0]); split2(v.y, h[1], l[1]);
  split2(v.z, h[2], l[2]); split2(v.w, h[3], l[3]);
  u16* o = out + (size_t)m * 1024 + c;
  *(uint2*)o = pack4(h);
  *(uint2*)(o + 512) = pack4(l);
}

__global__ __launch_bounds__(256) void split_rows(const float* __restrict__ in,
                                                  u16* __restrict__ out) {
  split_body(in, out, blockIdx.x * 256 + threadIdx.x);
}

__global__ __launch_bounds__(256) void split_w4(
    const float* __restrict__ w0, const float* __restrict__ w1,
    const float* __restrict__ w2, const float* __restrict__ w3,
    u16* __restrict__ out) {
  const int y = blockIdx.y;
  const float* src = (y == 0) ? w0 : (y == 1) ? w1 : (y == 2) ? w2 : w3;
  split_body(src, out + (size_t)y * 524288, blockIdx.x * 256 + threadIdx.x);
}

#define GLDS(g, l)                                                        \
  __builtin_amdgcn_global_load_lds(                                       \
      (const __attribute__((address_space(1))) void*)(g),                 \
      (__attribute__((address_space(3))) void*)(l), 16, 0, 0)

// =====================================================================
// Split-bf16 MFMA GEMM (validated in round 2): out = A @ B^T + bias.
// SPLIT_OUT=1: out u16 [m][1024] split planes, scaled. =0: fp32 [m][512].
// =====================================================================
template <int SPLIT_OUT>
__global__ __launch_bounds__(256) void gemm_split(
    const u16* __restrict__ A2, const u16* __restrict__ B2,
    const float* __restrict__ bias, void* __restrict__ outp, float scale) {
  __shared__ __align__(16) u16 Ah[4096], Al[4096], Bh[4096], Bl[4096];
  const int tid  = threadIdx.x;
  const int lane = tid & 63, w = tid >> 6;
  const int m0 = blockIdx.y * 64, n0 = blockIdx.x * 64;
  const int wm = (w & 1) * 32, wn = (w >> 1) * 32;

  const int sr  = w * 16 + (lane >> 3);
  const int scg = (lane & 7) ^ (sr & 7);
  const size_t aR = (size_t)(m0 + sr) * 1024 + scg * 8;
  const size_t bR = (size_t)(n0 + sr) * 1024 + scg * 8;
  const u16* gAh0 = A2 + aR;            const u16* gAh1 = A2 + aR + 8192;
  const u16* gAl0 = A2 + aR + 512;      const u16* gAl1 = A2 + aR + 8704;
  const u16* gBh0 = B2 + bR;            const u16* gBh1 = B2 + bR + 8192;
  const u16* gBl0 = B2 + bR + 512;      const u16* gBl1 = B2 + bR + 8704;
  char* lAh = (char*)Ah + w * 2048;  char* lAl = (char*)Al + w * 2048;
  char* lBh = (char*)Bh + w * 2048;  char* lBl = (char*)Bl + w * 2048;

  const int fr = lane & 15, kq = lane >> 4, fx = lane & 7;
  int aoff[2][2], boff[2][2];
#pragma unroll
  for (int s = 0; s < 2; ++s)
#pragma unroll
    for (int t = 0; t < 2; ++t) {
      aoff[s][t] = (wm + t * 16 + fr) * 64 + (((s * 4 + kq) ^ fx)) * 8;
      boff[s][t] = (wn + t * 16 + fr) * 64 + (((s * 4 + kq) ^ fx)) * 8;
    }

  f32x4 acc[2][2] = {};
  for (int k0 = 0; k0 < 512; k0 += 64) {
    __syncthreads();
    GLDS(gAh0 + k0, lAh);  GLDS(gAh1 + k0, lAh + 1024);
    GLDS(gAl0 + k0, lAl);  GLDS(gAl1 + k0, lAl + 1024);
    GLDS(gBh0 + k0, lBh);  GLDS(gBh1 + k0, lBh + 1024);
    GLDS(gBl0 + k0, lBl);  GLDS(gBl1 + k0, lBl + 1024);
    __syncthreads();
#pragma unroll
    for (int s = 0; s < 2; ++s) {
      bf16x8 ah[2], al[2], bh[2], bl[2];
#pragma unroll
      for (int t = 0; t < 2; ++t) {
        ah[t] = *(const bf16x8*)(Ah + aoff[s][t]);
        al[t] = *(const bf16x8*)(Al + aoff[s][t]);
        bh[t] = *(const bf16x8*)(Bh + boff[s][t]);
        bl[t] = *(const bf16x8*)(Bl + boff[s][t]);
      }
#pragma unroll
      for (int i = 0; i < 2; ++i)
#pragma unroll
        for (int j = 0; j < 2; ++j) {
          acc[i][j] = MFMA(al[i], bh[j], acc[i][j]);
          acc[i][j] = MFMA(ah[i], bl[j], acc[i][j]);
          acc[i][j] = MFMA(ah[i], bh[j], acc[i][j]);
        }
    }
  }

  const int er = (lane >> 4) * 4, ec = lane & 15;
#pragma unroll
  for (int i = 0; i < 2; ++i)
#pragma unroll
    for (int j = 0; j < 2; ++j) {
      const int row = m0 + wm + i * 16 + er;
      const int col = n0 + wn + j * 16 + ec;
      const float bv = bias[col];
#pragma unroll
      for (int r = 0; r < 4; ++r) {
        const float v = (acc[i][j][r] + bv) * scale;
        if (SPLIT_OUT) {
          u16 hh, ll; split2(v, hh, ll);
          u16* o = (u16*)outp;
          o[(size_t)(row + r) * 1024 + col] = hh;
          o[(size_t)(row + r) * 1024 + 512 + col] = ll;
        } else {
          ((float*)outp)[(size_t)(row + r) * 512 + col] = v;
        }
      }
    }
}

// =====================================================================
// Transpose V (split planes) to vt[(b*512+d)][pl*1024 + k].
// =====================================================================
__global__ __launch_bounds__(256) void vtbuild(const u16* __restrict__ v2,
                                               u16* __restrict__ vt) {
  __shared__ u16 Ts[2][64][72];
  const int t = threadIdx.x;
  const int b = blockIdx.z, d0 = blockIdx.y * 64, k0 = blockIdx.x * 64;
  const int r = t >> 3, c8 = (t & 7) * 8;
#pragma unroll
  for (int half = 0; half < 2; ++half) {
    const int kk = r + half * 32;
    const size_t row = (size_t)(b * 1024 + k0 + kk) * 1024;
#pragma unroll
    for (int pl = 0; pl < 2; ++pl)
      *(uint4*)&Ts[pl][kk][c8] = *(const uint4*)(v2 + row + pl * 512 + d0 + c8);
  }
  __syncthreads();
#pragma unroll
  for (int half = 0; half < 2; ++half) {
    const int dd = r + half * 32;
#pragma unroll
    for (int pl = 0; pl < 2; ++pl) {
      u16 tmp[8];
#pragma unroll
      for (int i = 0; i < 8; ++i) tmp[i] = Ts[pl][c8 + i][dd];
      *(uint4*)(vt + (size_t)(b * 512 + d0 + dd) * 2048 + pl * 1024 + k0 + c8) =
          *(uint4*)tmp;
    }
  }
}

// =====================================================================
// MFMA differential flash attention. Block = (32q, hp, b), 4 waves =
// (head h, q-tile qt). S^T via MFMA (A=K, B=Q-regs) -> online softmax in
// C-layout (q=lane, k=regs) -> split-bf16 P to LDS -> PV (A=Vt, B=P).
// Y1=P1V1 (w0), Y3=P2V2 (w1), Y2=P2V1 split 2+2 d-tiles across waves.
// All LDS rows 128B, XOR-8 chunk swizzle (<=2-way conflicts).
// =====================================================================
__global__ __launch_bounds__(256) void attn_mfma(
    const u16* __restrict__ q2, const u16* __restrict__ k2,
    const u16* __restrict__ vtg, const int* __restrict__ cq,
    const int* __restrict__ ck, const float* __restrict__ amap,
    const float* __restrict__ lq1, const float* __restrict__ lk1,
    const float* __restrict__ lq2, const float* __restrict__ lk2,
    const float* __restrict__ rpe, u16* __restrict__ xo) {
  __shared__ __align__(16) u16 KsL[8192];   // [h][pl][k 32][d-chunks] 16KB
  __shared__ __align__(16) u16 VtL[8192];   // [h][d 64][hi32k|lo32k]  16KB
  __shared__ __align__(16) u16 PsL[4096];   // [h][q 32][hi32k|lo32k]   8KB
  __shared__ int2 cks[32];
  __shared__ float a2s[2][16];
  __shared__ float l2s[2][16];
  __shared__ float y2x[2][64][8];
  __shared__ float lam_s;

  const int tid = threadIdx.x;
  const int lane = tid & 63, w = tid >> 6;
  const int h = w >> 1, qt = w & 1;
  const int b = blockIdx.z, hp = blockIdx.y;
  const int q0 = blockIdx.x * 32;
  const int head = hp + 4 * h;
  const int lq = lane & 15, lg = lane >> 4;
  const int q = qt * 16 + lq;
  const size_t qrow = (size_t)(b * NSEQ + q0 + q);

  // lambda for this head pair
  if (tid < 64) {
    float p1 = lq1[hp * 64 + tid] * lk1[hp * 64 + tid];
    float p2 = lq2[hp * 64 + tid] * lk2[hp * 64 + tid];
#pragma unroll
    for (int m = 32; m >= 1; m >>= 1) {
      p1 += __shfl_xor(p1, m, 64);
      p2 += __shfl_xor(p2, m, 64);
    }
    if (tid == 0) lam_s = __expf(p1) - __expf(p2) + 0.8f;
  }

  // per-lane preloads (q fixed per lane)
  const int cq0 = cq[qrow * 2 + 0];
  const int cq1 = cq[qrow * 2 + 1];
  const float alpha = amap[qrow];

  // Q B-frags in registers (q2 is pre-scaled by 1/8 in the Q-GEMM)
  bf16x8 Qf[2][2];
#pragma unroll
  for (int ks = 0; ks < 2; ++ks)
#pragma unroll
    for (int pl = 0; pl < 2; ++pl)
      Qf[ks][pl] = *(const bf16x8*)(q2 + qrow * 1024 + pl * 512 + head * 64 +
                                    ks * 32 + lg * 8);

  f32x4 Ya[4] = {};  // w0: Y1 ; w1: Y3
  f32x4 Yb[2] = {};  // w0: Y2 d-tiles 0,1 ; w1: Y2 d-tiles 2,3
  float m_run = -1e30f, l_run = 0.0f;

  const int sgrp = lane >> 3;             // staging row-in-group
  const int scc  = (lane & 7) ^ sgrp;     // staging chunk (xor-swizzled)

  for (int it = 0; it < NSEQ / 32; ++it) {
    const int k0 = it * 32;
    __syncthreads();  // A: prior PV reads done
    // ---- stage K (both heads, both planes) ----
#pragma unroll
    for (int i = 0; i < 4; ++i) {
      const int c16 = w * 4 + i;
      const int sh = c16 >> 3, spl = (c16 >> 2) & 1, sub = c16 & 3;
      const int r = sub * 8 + sgrp;
      const u16* src = k2 + (size_t)(b * NSEQ + k0 + r) * 1024 + spl * 512 +
                       (hp + 4 * sh) * 64 + scc * 8;
      GLDS(src, (char*)KsL + c16 * 1024);
    }
    // ---- stage Vt (both heads; plane/k-chunk from swizzled chunk id) ----
#pragma unroll
    for (int i = 0; i < 4; ++i) {
      const int c16 = w * 4 + i;
      const int sh = c16 >> 3, dg = c16 & 7;
      const int d = dg * 8 + sgrp;
      const int spl = scc >> 2, kc = scc & 3;
      const u16* src = vtg + (size_t)(b * 512 + (hp + 4 * sh) * 64 + d) * 2048 +
                       spl * 1024 + k0 + kc * 8;
      GLDS(src, (char*)VtL + c16 * 1024);
    }
    if (tid < 32) cks[tid] = ((const int2*)ck)[b * NSEQ + k0 + tid];
    __syncthreads();  // B: staging visible

    // ---- S^T = K . Q^T (3-term split) ----
    f32x4 st[2] = {};
#pragma unroll
    for (int kt = 0; kt < 2; ++kt) {
      const int krow = kt * 16 + lq;
#pragma unroll
      for (int ks = 0; ks < 2; ++ks) {
        const int phys = (ks * 4 + lg) ^ (krow & 7);
        const bf16x8 khi = *(const bf16x8*)(KsL + ((h * 2 + 0) * 32 + krow) * 64 + phys * 8);
        const bf16x8 klo = *(const bf16x8*)(KsL + ((h * 2 + 1) * 32 + krow) * 64 + phys * 8);
        st[kt] = MFMA(khi, Qf[ks][1], st[kt]);
        st[kt] = MFMA(klo, Qf[ks][0], st[kt]);
        st[kt] = MFMA(khi, Qf[ks][0], st[kt]);
      }
    }

    // ---- bias gather + dual online softmax (q = lane, k = regs) ----
    float sv[2][4];
    float mx = -1e30f;
#pragma unroll
    for (int kt = 0; kt < 2; ++kt)
#pragma unroll
      for (int r = 0; r < 4; ++r) {
        const int k = kt * 16 + lg * 4 + r;
        const int2 c = cks[k];
        const int r0 = min(max(cq0 - c.x + 128, 0), 256);
        const int r1 = min(max(cq1 - c.y + 128, 0), 256);
        const float s = st[kt][r] + rpe[(r0 * 257 + r1) * 8 + head];
        sv[kt][r] = s;
        mx = fmaxf(mx, s);
      }
    mx = fmaxf(mx, __shfl_xor(mx, 16, 64));
    mx = fmaxf(mx, __shfl_xor(mx, 32, 64));
    const float mnew = fmaxf(m_run, mx);
    const float a = __expf(m_run - mnew);
    m_run = mnew;
    float p[2][4], ps = 0.0f;
#pragma unroll
    for (int kt = 0; kt < 2; ++kt)
#pragma unroll
      for (int r = 0; r < 4; ++r) {
        p[kt][r] = __expf(sv[kt][r] - mnew);
        ps += p[kt][r];
      }
    ps += __shfl_xor(ps, 16, 64);
    ps += __shfl_xor(ps, 32, 64);
    l_run = l_run * a + ps;
    // rescale own accumulators
#pragma unroll
    for (int dt = 0; dt < 4; ++dt) Ya[dt] *= a;
    if (h == 1) { Yb[0] *= a; Yb[1] *= a; }
    if (h == 1 && lane < 16) a2s[qt][lane] = a;

    // ---- write split-bf16 P to LDS ----
#pragma unroll
    for (int kt = 0; kt < 2; ++kt) {
      u16 hh[4], ll[4];
#pragma unroll
      for (int r = 0; r < 4; ++r) split2(p[kt][r], hh[r], ll[r]);
      const int kc = kt * 2 + (lg >> 1);
      const int base = (h * 32 + q) * 64 + (lg & 1) * 4;
      *(uint2*)(PsL + base + ((kc ^ (q & 7)) * 8)) = pack4(hh);
      *(uint2*)(PsL + base + (((4 + kc) ^ (q & 7)) * 8)) = pack4(ll);
    }
    __syncthreads();  // C: P visible

    // ---- PV ----
    const int qx = q & 7;
    const bf16x8 p2h = *(const bf16x8*)(PsL + (32 + q) * 64 + ((0 * 4 + lg) ^ qx) * 8);
    const bf16x8 p2l = *(const bf16x8*)(PsL + (32 + q) * 64 + ((1 * 4 + lg) ^ qx) * 8);
    if (h == 0) {
      const float a2 = a2s[qt][lq];
      Yb[0] *= a2; Yb[1] *= a2;
      const bf16x8 p1h = *(const bf16x8*)(PsL + q * 64 + ((0 * 4 + lg) ^ qx) * 8);
      const bf16x8 p1l = *(const bf16x8*)(PsL + q * 64 + ((1 * 4 + lg) ^ qx) * 8);
#pragma unroll
      for (int dt = 0; dt < 4; ++dt) {
        const int d = dt * 16 + lq;
        const bf16x8 vh = *(const bf16x8*)(VtL + d * 64 + ((0 * 4 + lg) ^ (d & 7)) * 8);
        const bf16x8 vl = *(const bf16x8*)(VtL + d * 64 + ((1 * 4 + lg) ^ (d & 7)) * 8);
        Ya[dt] = MFMA(vh, p1l, Ya[dt]);
        Ya[dt] = MFMA(vl, p1h, Ya[dt]);
        Ya[dt] = MFMA(vh, p1h, Ya[dt]);
        if (dt < 2) {
          Yb[dt] = MFMA(vh, p2l, Yb[dt]);
          Yb[dt] = MFMA(vl, p2h, Yb[dt]);
          Yb[dt] = MFMA(vh, p2h, Yb[dt]);
        }
      }
    } else {
#pragma unroll
      for (int dt = 0; dt < 4; ++dt) {
        const int d = dt * 16 + lq;
        const bf16x8 vh = *(const bf16x8*)(VtL + (64 + d) * 64 + ((0 * 4 + lg) ^ (d & 7)) * 8);
        const bf16x8 vl = *(const bf16x8*)(VtL + (64 + d) * 64 + ((1 * 4 + lg) ^ (d & 7)) * 8);
        Ya[dt] = MFMA(vh, p2l, Ya[dt]);
        Ya[dt] = MFMA(vl, p2h, Ya[dt]);
        Ya[dt] = MFMA(vh, p2h, Ya[dt]);
      }
#pragma unroll
      for (int dt = 2; dt < 4; ++dt) {
        const int d = dt * 16 + lq;
        const bf16x8 vh = *(const bf16x8*)(VtL + d * 64 + ((0 * 4 + lg) ^ (d & 7)) * 8);
        const bf16x8 vl = *(const bf16x8*)(VtL + d * 64 + ((1 * 4 + lg) ^ (d & 7)) * 8);
        Yb[dt - 2] = MFMA(vh, p2l, Yb[dt - 2]);
        Yb[dt - 2] = MFMA(vl, p2h, Yb[dt - 2]);
        Yb[dt - 2] = MFMA(vh, p2h, Yb[dt - 2]);
      }
    }
  }

  // ---- epilogue: exchange Y2 halves + l2, combine, emit split-bf16 ----
  if (h == 1) {
    if (lane < 16) l2s[qt][lane] = l_run;
#pragma unroll
    for (int e = 0; e < 4; ++e) {
      y2x[qt][lane][e] = Yb[0][e];
      y2x[qt][lane][4 + e] = Yb[1][e];
    }
  }
  __syncthreads();

  if (h == 1) {
    const float inv2 = 1.0f / l_run;
#pragma unroll
    for (int dt = 0; dt < 4; ++dt) {
      u16 hh[4], ll[4];
#pragma unroll
      for (int r = 0; r < 4; ++r) split2(Ya[dt][r] * inv2, hh[r], ll[r]);
      u16* o = xo + qrow * 1024 + (hp + 4) * 64 + dt * 16 + lg * 4;
      *(uint2*)o = pack4(hh);
      *(uint2*)(o + 512) = pack4(ll);
    }
  } else {
    const float inv1 = 1.0f / l_run;
    const float inv2 = 1.0f / l2s[qt][lq];
    const float lam = lam_s;
    const float c1 = (1.0f + alpha) * inv1;
    const float c2 = alpha * lam * inv2;
#pragma unroll
    for (int dt = 0; dt < 4; ++dt) {
      u16 hh[4], ll[4];
#pragma unroll
      for (int r = 0; r < 4; ++r) {
        const float y2 = (dt < 2) ? Yb[dt][r] : y2x[qt][lane][(dt - 2) * 4 + r];
        split2(c1 * Ya[dt][r] - c2 * y2, hh[r], ll[r]);
      }
      u16* o = xo + qrow * 1024 + hp * 64 + dt * 16 + lg * 4;
      *(uint2*)o = pack4(hh);
      *(uint2*)(o + 512) = pack4(ll);
    }
  }
}

// =====================================================================
extern "C" void kernel_launch(void* const* d_in, const int* in_sizes, int n_in,
                              void* d_out, int out_size, void* d_ws, size_t ws_size,
                              hipStream_t stream) {
  const float* x_q   = (const float*)d_in[0];
  const float* x_kv  = (const float*)d_in[1];
  const int*   c_q   = (const int*)d_in[2];
  const int*   c_k   = (const int*)d_in[3];
  const float* alpha = (const float*)d_in[4];
  const float* Wq    = (const float*)d_in[5];
  const float* bq    = (const float*)d_in[6];
  const float* Wk    = (const float*)d_in[7];
  const float* bk    = (const float*)d_in[8];
  const float* Wv    = (const float*)d_in[9];
  const float* bv    = (const float*)d_in[10];
  const float* lq1   = (const float*)d_in[11];
  const float* lk1   = (const float*)d_in[12];
  const float* lq2   = (const float*)d_in[13];
  const float* lk2   = (const float*)d_in[14];
  const float* rpe   = (const float*)d_in[15];
  const float* Wp    = (const float*)d_in[16];
  const float* bp    = (const float*)d_in[17];
  float* out = (float*)d_out;

  // ws (28 MB): w2[0..4M) | slot1[4..12M) xq2->v2->xa2 | slot2[12..20M)
  // xkv2->vt | slot3[20..28M) k2.  q2 lives in d_out (8 MB) until final GEMM.
  u16* w2    = (u16*)d_ws;
  u16* slot1 = (u16*)((char*)d_ws + (4u << 20));
  u16* slot2 = (u16*)((char*)d_ws + (12u << 20));
  u16* slot3 = (u16*)((char*)d_ws + (20u << 20));
  u16* q2    = (u16*)d_out;

  const dim3 gg(8, 64);
  split_w4<<<dim3(256, 4), 256, 0, stream>>>(Wq, Wk, Wv, Wp, w2);
  split_rows<<<2048, 256, 0, stream>>>(x_q, slot1);
  gemm_split<1><<<gg, 256, 0, stream>>>(slot1, w2, bq, q2, 0.125f);
  split_rows<<<2048, 256, 0, stream>>>(x_kv, slot2);
  gemm_split<1><<<gg, 256, 0, stream>>>(slot2, w2 + 524288, bk, slot3, 1.0f);
  gemm_split<1><<<gg, 256, 0, stream>>>(slot2, w2 + 2 * 524288, bv, slot1, 1.0f);
  vtbuild<<<dim3(16, 8, 4), 256, 0, stream>>>(slot1, slot2);
  attn_mfma<<<dim3(32, 4, 4), 256, 0, stream>>>(
      q2, slot3, slot2, c_q, c_k, alpha, lq1, lk1, lq2, lk2, rpe, slot1);
  gemm_split<0><<<gg, 256, 0, stream>>>(slot1, w2 + 3 * 524288, bp, out, 1.0f);
}